// Round 13
// baseline (450.286 us; speedup 1.0000x reference)
//
#include <hip/hip_runtime.h>

#define CDIV(a,b) (((a)+(b)-1)/(b))

typedef __bf16 bf16x8 __attribute__((ext_vector_type(8)));
typedef float  f32x4  __attribute__((ext_vector_type(4)));

__device__ __forceinline__ ushort f2bf(float f) {
    uint u = __float_as_uint(f);
    uint r = u + 0x7fffu + ((u >> 16) & 1u);   // RNE
    return (ushort)(r >> 16);
}
__device__ __forceinline__ float bf_lo(uint p) { return __uint_as_float(p << 16); }
__device__ __forceinline__ float bf_hi(uint p) { return __uint_as_float(p & 0xffff0000u); }

__device__ __forceinline__ void glds16(const void* g, void* l) {
    __builtin_amdgcn_global_load_lds(
        (const __attribute__((address_space(1))) void*)g,
        (__attribute__((address_space(3))) void*)l, 16, 0, 0);
}

// ================= CSR build via 256-node buckets (dual-graph) =================

__global__ __launch_bounds__(256) void binA_k(const int* __restrict__ ei0,
                                              const int* __restrict__ ei1,
                                              int E0, int E1, int NB, int CAP, int gbase,
                                              int* __restrict__ bcur, int bstr,
                                              uint* __restrict__ binned, size_t binstr) {
    const int g = gbase + blockIdx.y;
    const int* srcp = g ? ei1 : ei0;
    const int  E    = g ? E1 : E0;
    const int e0 = blockIdx.x * 4096;
    if (e0 >= E) return;
    const int* dstp = srcp + E;
    int*  bc = bcur + (size_t)g * bstr;
    uint* bn = binned + (size_t)g * binstr;

    __shared__ uint hist[512];
    __shared__ uint cur[512];
    const int t = threadIdx.x;
    for (int i = t; i < NB; i += 256) hist[i] = 0;
    __syncthreads();

    const int e1 = min(e0 + 4096, E);
    for (int e = e0 + t; e < e1; e += 256)
        atomicAdd(&hist[dstp[e] >> 8], 1u);
    __syncthreads();

    for (int i = t; i < NB; i += 256) {
        uint c = hist[i];
        cur[i] = c ? (uint)atomicAdd(&bc[i], (int)c) : 0u;
    }
    __syncthreads();

    for (int e = e0 + t; e < e1; e += 256) {
        int d = dstp[e];
        int b = d >> 8;
        uint p = atomicAdd(&cur[b], 1u);
        if (p < (uint)CAP)
            bn[(size_t)b * CAP + p] = ((uint)srcp[e] << 8) | (uint)(d & 255);
    }
}

__global__ __launch_bounds__(256) void binB_k(const uint* __restrict__ binned, size_t binstr,
                                              const int* __restrict__ bcur, int bstr,
                                              int N, int CAP, int gbase,
                                              int* __restrict__ csr, size_t cstr,
                                              int* __restrict__ start,
                                              int* __restrict__ degc,
                                              float* __restrict__ dinv, int nstr) {
    const int g = gbase + blockIdx.y;
    const int b = blockIdx.x;
    const int t = threadIdx.x;
    int cnt = bcur[(size_t)g * bstr + b];
    if (cnt > CAP) cnt = CAP;
    const uint* be = binned + (size_t)g * binstr + (size_t)b * CAP;
    int*   csr_g  = csr  + (size_t)g * cstr;
    int*   st_g   = start + (size_t)g * nstr;
    int*   dg_g   = degc  + (size_t)g * nstr;
    float* dv_g   = dinv  + (size_t)g * nstr;

    __shared__ uint hist[256];
    __shared__ uint cur[256];
    __shared__ uint wsum[4];

    hist[t] = 0;
    __syncthreads();
    for (int e = t; e < cnt; e += 256) atomicAdd(&hist[be[e] & 255u], 1u);
    __syncthreads();

    uint v = hist[t];
    uint inc = v;
#pragma unroll
    for (int off = 1; off < 64; off <<= 1) {
        uint n = __shfl_up(inc, off);
        if ((t & 63) >= off) inc += n;
    }
    if ((t & 63) == 63) wsum[t >> 6] = inc;
    __syncthreads();
    uint wo = 0;
    if ((t >> 6) >= 1) wo += wsum[0];
    if ((t >> 6) >= 2) wo += wsum[1];
    if ((t >> 6) >= 3) wo += wsum[2];
    uint excl = wo + inc - v;
    cur[t] = excl;
    __syncthreads();

    const int base = b * CAP;
    for (int e = t; e < cnt; e += 256) {
        uint w = be[e];
        uint p = atomicAdd(&cur[w & 255u], 1u);
        csr_g[base + (int)p] = (int)(w >> 8);
    }

    int node = b * 256 + t;
    if (node < N) {
        st_g[node] = base + (int)excl;
        dg_g[node] = (int)v;
        dv_g[node] = rsqrtf((float)(v + 1));
    }
}

// ================= W pre-pack: fragment-major bf16 =================

__global__ __launch_bounds__(256) void pack_w_k(const float* __restrict__ W,
                                                ushort* __restrict__ Wp, int K) {
    int idx = blockIdx.x * 256 + threadIdx.x;
    int total = (K / 32) * 8 * 64;
    if (idx >= total) return;
    int l  = idx & 63;
    int nf = (idx >> 6) & 7;
    int kb = idx >> 9;
    int col = nf * 16 + (l & 15);
    int k0  = kb * 32 + (l >> 4) * 8;
    ushort o[8];
#pragma unroll
    for (int j = 0; j < 8; ++j) o[j] = f2bf(W[(size_t)(k0 + j) * 128 + col]);
    *reinterpret_cast<float4*>(Wp + (size_t)idx * 8) = *reinterpret_cast<float4*>(o);
}

// ===== MFMA GEMM: C[r] = dinv[r]*(X[r]@W), 64-row tile, whole-K LDS via glds =====
// Epilogue: LDS-bounce transpose (row stride 136 ushorts) -> coalesced 16B stores.
// LDS sized for BOTH uses: staging tile (64*ROWB) and bounce buffer (64*136*2).

template <int K, typename TIn>
__global__ __launch_bounds__(256) void gemm_mfma(const TIn* __restrict__ X0,
                                                 const TIn* __restrict__ X1,
                                                 const float4* __restrict__ Wp,
                                                 const float* __restrict__ dinv, int nstr,
                                                 ushort* __restrict__ C, size_t hstr,
                                                 int N, int gbase) {
    constexpr int ROWB = K * (int)sizeof(TIn);
    constexpr int LDSB = (64 * ROWB > 64 * 136 * 2) ? 64 * ROWB : 64 * 136 * 2;
    __shared__ char As[LDSB];             // 64KB (f32 K=256) / 17.4KB (bf16 K=128)

    const int g = gbase + blockIdx.y;
    const TIn* X = g ? X1 : X0;
    const float* dv = dinv + (size_t)g * nstr;
    ushort* Cg = C + (size_t)g * hstr;

    const int t    = threadIdx.x;
    const int lane = t & 63;
    const int w    = t >> 6;
    const int row0 = blockIdx.x * 64;

    if constexpr (sizeof(TIn) == 4) {
#pragma unroll
        for (int i = 0; i < 16; ++i) {
            int rr   = w * 16 + i;
            int grow = min(row0 + rr, N - 1);
            const float* src = (const float*)X + (size_t)grow * K + (size_t)(lane ^ (i & 7)) * 4;
            glds16(src, As + (size_t)rr * ROWB);
        }
    } else {
#pragma unroll
        for (int i = 0; i < 4; ++i) {
            int rr   = w * 16 + i * 4 + (lane >> 4);
            int grow = min(row0 + rr, N - 1);
            int slot = (lane & 15) ^ (rr & 7);
            const ushort* src = (const ushort*)X + (size_t)grow * K + (size_t)slot * 8;
            glds16(src, As + (size_t)(w * 16 + i * 4) * ROWB);
        }
    }
    __syncthreads();

    f32x4 acc[8] = {};
    const int r  = w * 16 + (lane & 15);
    const int kc = lane >> 4;

#pragma unroll
    for (int kb = 0; kb < K / 32; ++kb) {
        bf16x8 bfr[8];
#pragma unroll
        for (int nf = 0; nf < 8; ++nf)
            bfr[nf] = *reinterpret_cast<const bf16x8*>(Wp + (size_t)(kb * 8 + nf) * 64 + lane);

        bf16x8 a;
        if constexpr (sizeof(TIn) == 4) {
            int s0 = (kb * 8 + kc * 2) ^ (r & 7);
            int s1 = (kb * 8 + kc * 2 + 1) ^ (r & 7);
            f32x4 a0 = *reinterpret_cast<const f32x4*>(&As[(size_t)r * ROWB + (size_t)s0 * 16]);
            f32x4 a1 = *reinterpret_cast<const f32x4*>(&As[(size_t)r * ROWB + (size_t)s1 * 16]);
            a[0] = (__bf16)a0[0]; a[1] = (__bf16)a0[1]; a[2] = (__bf16)a0[2]; a[3] = (__bf16)a0[3];
            a[4] = (__bf16)a1[0]; a[5] = (__bf16)a1[1]; a[6] = (__bf16)a1[2]; a[7] = (__bf16)a1[3];
        } else {
            int s = (kb * 4 + kc) ^ (r & 7);
            a = *reinterpret_cast<const bf16x8*>(&As[(size_t)r * ROWB + (size_t)s * 16]);
        }

#pragma unroll
        for (int nf = 0; nf < 8; ++nf)
            acc[nf] = __builtin_amdgcn_mfma_f32_16x16x32_bf16(a, bfr[nf], acc[nf], 0, 0, 0);
    }

    // ---- epilogue: fragments -> LDS (stride 136) -> coalesced 16B stores ----
    __syncthreads();                                   // done reading staged A
    ushort* Cs = reinterpret_cast<ushort*>(As);        // 64 x 136 ushorts = 17.4 KB

    {
        const int lr0 = w * 16 + ((lane >> 4) << 2);
        const int col = lane & 15;
#pragma unroll
        for (int i = 0; i < 4; ++i) {
            int row = row0 + lr0 + i;
            float dr = (row < N) ? dv[row] : 0.f;
#pragma unroll
            for (int nf = 0; nf < 8; ++nf)
                Cs[(lr0 + i) * 136 + nf * 16 + col] = f2bf(acc[nf][i] * dr);
        }
    }
    __syncthreads();

    {
        const int lr = t >> 2;                          // local row (4 threads/row)
        const int c0 = (t & 3) * 4;                     // first 16B chunk
        const int row = row0 + lr;
        if (row < N) {
#pragma unroll
            for (int j = 0; j < 4; ++j) {
                int ch = c0 + j;
                float4 vv = *reinterpret_cast<const float4*>(&Cs[lr * 136 + ch * 8]);
                *reinterpret_cast<float4*>(Cg + (size_t)row * 128 + ch * 8) = vv;
            }
        }
    }
}

// ===== aggregation: unweighted sum of pre-scaled bf16 rows =====

template <int RELU>
__global__ __launch_bounds__(256) void agg_k(const ushort* __restrict__ Hin, size_t hstr,
                                             ushort* __restrict__ Hout,
                                             const int* __restrict__ csr, size_t cstr,
                                             const int* __restrict__ start,
                                             const int* __restrict__ degc,
                                             const float* __restrict__ dinv, int nstr,
                                             const float* __restrict__ bias,
                                             int N, int gbase) {
    const int g = gbase + blockIdx.y;
    const int wid  = threadIdx.x >> 6;
    const int lane = threadIdx.x & 63;
    const int v = blockIdx.x * 4 + wid;
    if (v >= N) return;

    const uint* base = reinterpret_cast<const uint*>(Hin + (size_t)g * hstr);
    const int*  cs   = csr + (size_t)g * cstr;
    float dvv = dinv[(size_t)g * nstr + v];
    int s   = start[(size_t)g * nstr + v];
    int end = s + degc[(size_t)g * nstr + v];

    uint hp = base[(size_t)v * 64 + lane];
    float ax = bf_lo(hp);
    float ay = bf_hi(hp);

    for (int bs = s; bs < end; bs += 64) {
        int m = end - bs;
        if (m > 64) m = 64;
        int u_l = 0;
        if (lane < m) u_l = cs[bs + lane];
        int e = 0;
        for (; e + 8 <= m; e += 8) {
            uint p[8];
#pragma unroll
            for (int j = 0; j < 8; ++j) {
                int u = __shfl(u_l, e + j);
                p[j] = base[(size_t)u * 64 + lane];
            }
#pragma unroll
            for (int j = 0; j < 8; ++j) { ax += bf_lo(p[j]); ay += bf_hi(p[j]); }
        }
        if (e + 4 <= m) {
            uint p[4];
#pragma unroll
            for (int j = 0; j < 4; ++j) {
                int u = __shfl(u_l, e + j);
                p[j] = base[(size_t)u * 64 + lane];
            }
#pragma unroll
            for (int j = 0; j < 4; ++j) { ax += bf_lo(p[j]); ay += bf_hi(p[j]); }
            e += 4;
        }
        for (; e < m; ++e) {
            int u = __shfl(u_l, e);
            uint p = base[(size_t)u * 64 + lane];
            ax += bf_lo(p);
            ay += bf_hi(p);
        }
    }

    float2 b = reinterpret_cast<const float2*>(bias)[lane];
    float ox = fmaf(dvv, ax, b.x);
    float oy = fmaf(dvv, ay, b.y);
    if (RELU) {
        ox = fmaxf(ox, 0.f);
        oy = fmaxf(oy, 0.f);
    }
    uint packed = (uint)f2bf(ox) | ((uint)f2bf(oy) << 16);
    reinterpret_cast<uint*>(Hout + (size_t)g * hstr)[(size_t)v * 64 + lane] = packed;
}

// ===== column stats over bf16 H =====

__global__ __launch_bounds__(256) void colstats_k(const ushort* __restrict__ H, size_t hstr,
                                                  float* __restrict__ stats, int sstr,
                                                  int N, int gbase) {
    const int g = gbase + blockIdx.y;
    __shared__ float4 red[4][64];
    const int t  = threadIdx.x;
    const int cp = t & 63;
    const int rg = t >> 6;
    const int r0 = blockIdx.x * 512;
    const int r1 = min(r0 + 512, N);

    const uint* base = reinterpret_cast<const uint*>(H + (size_t)g * hstr);
    float sx = 0.f, qx = 0.f, sy = 0.f, qy = 0.f;
    for (int r = r0 + rg; r < r1; r += 4) {
        uint p = base[(size_t)r * 64 + cp];
        float a = bf_lo(p), b = bf_hi(p);
        sx += a; qx = fmaf(a, a, qx);
        sy += b; qy = fmaf(b, b, qy);
    }
    red[rg][cp] = make_float4(sx, qx, sy, qy);
    __syncthreads();
    if (rg == 0) {
        float4 a0 = red[0][cp], a1 = red[1][cp], a2 = red[2][cp], a3 = red[3][cp];
        float* st = stats + (size_t)g * sstr + (size_t)(blockIdx.x & 7) * 256;
        atomicAdd(&st[cp * 2],           a0.x + a1.x + a2.x + a3.x);
        atomicAdd(&st[cp * 2 + 1],       a0.z + a1.z + a2.z + a3.z);
        atomicAdd(&st[128 + cp * 2],     a0.y + a1.y + a2.y + a3.y);
        atomicAdd(&st[128 + cp * 2 + 1], a0.w + a1.w + a2.w + a3.w);
    }
}

// ================= colnorm: bf16 in -> f32 out =================

__global__ __launch_bounds__(256) void colnorm_k(const ushort* __restrict__ H, size_t hstr,
                                                 const float* __restrict__ stats, int sstr,
                                                 float* __restrict__ Out,
                                                 int N, int gbase) {
    const int g = gbase + blockIdx.y;
    __shared__ float mu_s[128], rs_s[128];
    const int t = threadIdx.x;
    const float* st = stats + (size_t)g * sstr;
    if (t < 128) {
        float s = 0.f, q = 0.f;
#pragma unroll
        for (int sl = 0; sl < 8; ++sl) {
            s += st[sl * 256 + t];
            q += st[sl * 256 + 128 + t];
        }
        float mu = s / (float)N;
        float var = (q - s * mu) / (float)(N - 1);
        mu_s[t] = mu;
        rs_s[t] = rsqrtf(var);
    }
    __syncthreads();

    const uint4* Hb = reinterpret_cast<const uint4*>(H + (size_t)g * hstr);
    float4* Ob = reinterpret_cast<float4*>(Out + (size_t)g * N * 128);
    size_t total = (size_t)N * 16;
    size_t stride = (size_t)gridDim.x * 256;
    for (size_t i = (size_t)blockIdx.x * 256 + t; i < total; i += stride) {
        uint4 p = Hb[i];
        int c0 = ((int)(i & 15)) * 8;
        float o[8] = {bf_lo(p.x), bf_hi(p.x), bf_lo(p.y), bf_hi(p.y),
                      bf_lo(p.z), bf_hi(p.z), bf_lo(p.w), bf_hi(p.w)};
        float4 r0, r1;
        r0.x = (o[0] - mu_s[c0 + 0]) * rs_s[c0 + 0];
        r0.y = (o[1] - mu_s[c0 + 1]) * rs_s[c0 + 1];
        r0.z = (o[2] - mu_s[c0 + 2]) * rs_s[c0 + 2];
        r0.w = (o[3] - mu_s[c0 + 3]) * rs_s[c0 + 3];
        r1.x = (o[4] - mu_s[c0 + 4]) * rs_s[c0 + 4];
        r1.y = (o[5] - mu_s[c0 + 5]) * rs_s[c0 + 5];
        r1.z = (o[6] - mu_s[c0 + 6]) * rs_s[c0 + 6];
        r1.w = (o[7] - mu_s[c0 + 7]) * rs_s[c0 + 7];
        Ob[i * 2]     = r0;
        Ob[i * 2 + 1] = r1;
    }
}

// ================= driver =================

extern "C" void kernel_launch(void* const* d_in, const int* in_sizes, int n_in,
                              void* d_out, int out_size, void* d_ws, size_t ws_size,
                              hipStream_t stream) {
    const float* x1  = (const float*)d_in[0];
    const int*   ei1 = (const int*)d_in[1];
    const float* x2  = (const float*)d_in[2];
    const int*   ei2 = (const int*)d_in[3];
    const float* W0  = (const float*)d_in[4];
    const float* b0  = (const float*)d_in[5];
    const float* W1  = (const float*)d_in[6];
    const float* b1  = (const float*)d_in[7];

    const int N  = in_sizes[0] / 256;
    const int E1 = in_sizes[1] / 2;
    const int E2 = in_sizes[3] / 2;
    const int Emax = E1 > E2 ? E1 : E2;

    const int NB = CDIV(N, 256);
    int cap = (Emax / NB) * 8 / 5 + 1024;
    const int CAP = (cap + 1023) & ~1023;

    size_t szH = (size_t)N * 128 * 2;
    size_t need_merged = 2 * szH * 2
                       + (size_t)2 * N * 4 * 3
                       + (size_t)2 * NB * CAP * 4
                       + 64 * 1024 + 32 * 1024
                       + 2 * 8 * 256 * 4 + 2 * NB * 4
                       + 16 * 256;
    const bool merged = ws_size >= need_merged;
    const int  G = merged ? 2 : 1;

    const size_t hstr   = merged ? (size_t)N * 128 : 0;
    const int    nstr   = merged ? N : 0;
    const size_t cstr   = merged ? (size_t)NB * CAP : 0;
    const int    bstr   = merged ? NB : 0;
    const int    sstr   = merged ? 8 * 256 : 0;
    const size_t binstr = merged ? (size_t)N * 64 : 0;

    char* base = (char*)d_ws;
    size_t off = 0;
    auto carve = [&](size_t bytes) -> char* {
        char* p = base + off;
        off = (off + bytes + 255) & ~(size_t)255;
        return p;
    };
    ushort* hA    = (ushort*)carve(szH * G);     // aliases binned
    ushort* hB    = (ushort*)carve(szH * G);
    float*  dinv  = (float*)carve((size_t)N * 4 * G);
    int*    degc  = (int*)carve((size_t)N * 4 * G);
    int*    startA= (int*)carve((size_t)N * 4 * G);
    int*    csr   = (int*)carve((size_t)NB * CAP * 4 * G);
    ushort* Wp0   = (ushort*)carve((256 / 32) * 8 * 64 * 8 * 2);
    ushort* Wp1   = (ushort*)carve((128 / 32) * 8 * 64 * 8 * 2);
    float*  stats = (float*)carve(8 * 256 * 4 * G);
    int*    bcur  = (int*)carve((size_t)NB * 4 * G);
    uint*   binned = (uint*)hA;

    pack_w_k<<<CDIV((256 / 32) * 8 * 64, 256), 256, 0, stream>>>(W0, Wp0, 256);
    pack_w_k<<<CDIV((128 / 32) * 8 * 64, 256), 256, 0, stream>>>(W1, Wp1, 128);

    const int npass = merged ? 1 : 2;
    for (int pass = 0; pass < npass; ++pass) {
        const int gbase = merged ? 0 : pass;

        hipMemsetAsync(bcur, 0, (size_t)NB * 4 * G, stream);
        hipMemsetAsync(stats, 0, 8 * 256 * 4 * G, stream);

        binA_k<<<dim3(CDIV(Emax, 4096), G), 256, 0, stream>>>(
            ei1, ei2, E1, E2, NB, CAP, gbase, bcur, bstr, binned, binstr);
        binB_k<<<dim3(NB, G), 256, 0, stream>>>(
            binned, binstr, bcur, bstr, N, CAP, gbase, csr, cstr, startA, degc, dinv, nstr);

        // conv1: hA = dinv .* (x @ W0) ; hB = relu(dinv.*sum + b0)  [bf16]
        gemm_mfma<256, float><<<dim3(CDIV(N, 64), G), 256, 0, stream>>>(
            x1, x2, (const float4*)Wp0, dinv, nstr, hA, hstr, N, gbase);
        agg_k<1><<<dim3(CDIV(N, 4), G), 256, 0, stream>>>(
            hA, hstr, hB, csr, cstr, startA, degc, dinv, nstr, b0, N, gbase);

        // conv2: hA = dinv .* (hB @ W1) ; hB = dinv.*sum + b1 [bf16]
        gemm_mfma<128, ushort><<<dim3(CDIV(N, 64), G), 256, 0, stream>>>(
            hB, hB + hstr, (const float4*)Wp1, dinv, nstr, hA, hstr, N, gbase);
        agg_k<0><<<dim3(CDIV(N, 4), G), 256, 0, stream>>>(
            hA, hstr, hB, csr, cstr, startA, degc, dinv, nstr, b1, N, gbase);

        // stats + colnorm: out = (hB - mu) / sd   [f32]
        colstats_k<<<dim3(CDIV(N, 512), G), 256, 0, stream>>>(
            hB, hstr, stats, sstr, N, gbase);
        colnorm_k<<<dim3(1024, G), 256, 0, stream>>>(
            hB, hstr, stats, sstr, (float*)d_out, N, gbase);
    }
}

// Round 14
// 420.067 us; speedup vs baseline: 1.0719x; 1.0719x over previous
//
#include <hip/hip_runtime.h>

#define CDIV(a,b) (((a)+(b)-1)/(b))

typedef __bf16 bf16x8 __attribute__((ext_vector_type(8)));
typedef float  f32x4  __attribute__((ext_vector_type(4)));

__device__ __forceinline__ ushort f2bf(float f) {
    uint u = __float_as_uint(f);
    uint r = u + 0x7fffu + ((u >> 16) & 1u);   // RNE
    return (ushort)(r >> 16);
}
__device__ __forceinline__ float bf_lo(uint p) { return __uint_as_float(p << 16); }
__device__ __forceinline__ float bf_hi(uint p) { return __uint_as_float(p & 0xffff0000u); }

__device__ __forceinline__ void glds16(const void* g, void* l) {
    __builtin_amdgcn_global_load_lds(
        (const __attribute__((address_space(1))) void*)g,
        (__attribute__((address_space(3))) void*)l, 16, 0, 0);
}

// ================= CSR build via 256-node buckets (dual-graph) =================

__global__ __launch_bounds__(256) void binA_k(const int* __restrict__ ei0,
                                              const int* __restrict__ ei1,
                                              int E0, int E1, int NB, int CAP, int gbase,
                                              int* __restrict__ bcur, int bstr,
                                              uint* __restrict__ binned, size_t binstr) {
    const int g = gbase + blockIdx.y;
    const int* srcp = g ? ei1 : ei0;
    const int  E    = g ? E1 : E0;
    const int e0 = blockIdx.x * 4096;
    if (e0 >= E) return;
    const int* dstp = srcp + E;
    int*  bc = bcur + (size_t)g * bstr;
    uint* bn = binned + (size_t)g * binstr;

    __shared__ uint hist[512];
    __shared__ uint cur[512];
    const int t = threadIdx.x;
    for (int i = t; i < NB; i += 256) hist[i] = 0;
    __syncthreads();

    const int e1 = min(e0 + 4096, E);
    for (int e = e0 + t; e < e1; e += 256)
        atomicAdd(&hist[dstp[e] >> 8], 1u);
    __syncthreads();

    for (int i = t; i < NB; i += 256) {
        uint c = hist[i];
        cur[i] = c ? (uint)atomicAdd(&bc[i], (int)c) : 0u;
    }
    __syncthreads();

    for (int e = e0 + t; e < e1; e += 256) {
        int d = dstp[e];
        int b = d >> 8;
        uint p = atomicAdd(&cur[b], 1u);
        if (p < (uint)CAP)
            bn[(size_t)b * CAP + p] = ((uint)srcp[e] << 8) | (uint)(d & 255);
    }
}

__global__ __launch_bounds__(256) void binB_k(const uint* __restrict__ binned, size_t binstr,
                                              const int* __restrict__ bcur, int bstr,
                                              int N, int CAP, int gbase,
                                              int* __restrict__ csr, size_t cstr,
                                              int* __restrict__ start,
                                              int* __restrict__ degc,
                                              float* __restrict__ dinv, int nstr) {
    const int g = gbase + blockIdx.y;
    const int b = blockIdx.x;
    const int t = threadIdx.x;
    int cnt = bcur[(size_t)g * bstr + b];
    if (cnt > CAP) cnt = CAP;
    const uint* be = binned + (size_t)g * binstr + (size_t)b * CAP;
    int*   csr_g  = csr  + (size_t)g * cstr;
    int*   st_g   = start + (size_t)g * nstr;
    int*   dg_g   = degc  + (size_t)g * nstr;
    float* dv_g   = dinv  + (size_t)g * nstr;

    __shared__ uint hist[256];
    __shared__ uint cur[256];
    __shared__ uint wsum[4];

    hist[t] = 0;
    __syncthreads();
    for (int e = t; e < cnt; e += 256) atomicAdd(&hist[be[e] & 255u], 1u);
    __syncthreads();

    uint v = hist[t];
    uint inc = v;
#pragma unroll
    for (int off = 1; off < 64; off <<= 1) {
        uint n = __shfl_up(inc, off);
        if ((t & 63) >= off) inc += n;
    }
    if ((t & 63) == 63) wsum[t >> 6] = inc;
    __syncthreads();
    uint wo = 0;
    if ((t >> 6) >= 1) wo += wsum[0];
    if ((t >> 6) >= 2) wo += wsum[1];
    if ((t >> 6) >= 3) wo += wsum[2];
    uint excl = wo + inc - v;
    cur[t] = excl;
    __syncthreads();

    const int base = b * CAP;
    for (int e = t; e < cnt; e += 256) {
        uint w = be[e];
        uint p = atomicAdd(&cur[w & 255u], 1u);
        csr_g[base + (int)p] = (int)(w >> 8);
    }

    int node = b * 256 + t;
    if (node < N) {
        st_g[node] = base + (int)excl;
        dg_g[node] = (int)v;
        dv_g[node] = rsqrtf((float)(v + 1));
    }
}

// ================= W pre-pack: fragment-major bf16 =================

__global__ __launch_bounds__(256) void pack_w_k(const float* __restrict__ W,
                                                ushort* __restrict__ Wp, int K) {
    int idx = blockIdx.x * 256 + threadIdx.x;
    int total = (K / 32) * 8 * 64;
    if (idx >= total) return;
    int l  = idx & 63;
    int nf = (idx >> 6) & 7;
    int kb = idx >> 9;
    int col = nf * 16 + (l & 15);
    int k0  = kb * 32 + (l >> 4) * 8;
    ushort o[8];
#pragma unroll
    for (int j = 0; j < 8; ++j) o[j] = f2bf(W[(size_t)(k0 + j) * 128 + col]);
    *reinterpret_cast<float4*>(Wp + (size_t)idx * 8) = *reinterpret_cast<float4*>(o);
}

// ===== MFMA GEMM: C[r] = dinv[r]*(X[r]@W), 64-row tile, whole-K LDS via glds =====

template <int K, typename TIn>
__global__ __launch_bounds__(256) void gemm_mfma(const TIn* __restrict__ X0,
                                                 const TIn* __restrict__ X1,
                                                 const float4* __restrict__ Wp,
                                                 const float* __restrict__ dinv, int nstr,
                                                 ushort* __restrict__ C, size_t hstr,
                                                 int N, int gbase) {
    constexpr int ROWB = K * (int)sizeof(TIn);
    __shared__ char As[64 * ROWB];

    const int g = gbase + blockIdx.y;
    const TIn* X = g ? X1 : X0;
    const float* dv = dinv + (size_t)g * nstr;
    ushort* Cg = C + (size_t)g * hstr;

    const int t    = threadIdx.x;
    const int lane = t & 63;
    const int w    = t >> 6;
    const int row0 = blockIdx.x * 64;

    if constexpr (sizeof(TIn) == 4) {
#pragma unroll
        for (int i = 0; i < 16; ++i) {
            int rr   = w * 16 + i;
            int grow = min(row0 + rr, N - 1);
            const float* src = (const float*)X + (size_t)grow * K + (size_t)(lane ^ (i & 7)) * 4;
            glds16(src, As + (size_t)rr * ROWB);
        }
    } else {
#pragma unroll
        for (int i = 0; i < 4; ++i) {
            int rr   = w * 16 + i * 4 + (lane >> 4);
            int grow = min(row0 + rr, N - 1);
            int slot = (lane & 15) ^ (rr & 7);
            const ushort* src = (const ushort*)X + (size_t)grow * K + (size_t)slot * 8;
            glds16(src, As + (size_t)(w * 16 + i * 4) * ROWB);
        }
    }
    __syncthreads();

    f32x4 acc[8] = {};
    const int r  = w * 16 + (lane & 15);
    const int kc = lane >> 4;

#pragma unroll
    for (int kb = 0; kb < K / 32; ++kb) {
        bf16x8 bfr[8];
#pragma unroll
        for (int nf = 0; nf < 8; ++nf)
            bfr[nf] = *reinterpret_cast<const bf16x8*>(Wp + (size_t)(kb * 8 + nf) * 64 + lane);

        bf16x8 a;
        if constexpr (sizeof(TIn) == 4) {
            int s0 = (kb * 8 + kc * 2) ^ (r & 7);
            int s1 = (kb * 8 + kc * 2 + 1) ^ (r & 7);
            f32x4 a0 = *reinterpret_cast<const f32x4*>(&As[(size_t)r * ROWB + (size_t)s0 * 16]);
            f32x4 a1 = *reinterpret_cast<const f32x4*>(&As[(size_t)r * ROWB + (size_t)s1 * 16]);
            a[0] = (__bf16)a0[0]; a[1] = (__bf16)a0[1]; a[2] = (__bf16)a0[2]; a[3] = (__bf16)a0[3];
            a[4] = (__bf16)a1[0]; a[5] = (__bf16)a1[1]; a[6] = (__bf16)a1[2]; a[7] = (__bf16)a1[3];
        } else {
            int s = (kb * 4 + kc) ^ (r & 7);
            a = *reinterpret_cast<const bf16x8*>(&As[(size_t)r * ROWB + (size_t)s * 16]);
        }

#pragma unroll
        for (int nf = 0; nf < 8; ++nf)
            acc[nf] = __builtin_amdgcn_mfma_f32_16x16x32_bf16(a, bfr[nf], acc[nf], 0, 0, 0);
    }

    const int rb = row0 + w * 16 + ((lane >> 4) << 2);
#pragma unroll
    for (int i = 0; i < 4; ++i) {
        int row = rb + i;
        if (row < N) {
            float dr = dv[row];
#pragma unroll
            for (int nf = 0; nf < 8; ++nf)
                Cg[(size_t)row * 128 + nf * 16 + (lane & 15)] = f2bf(acc[nf][i] * dr);
        }
    }
}

// ===== aggregation: unweighted sum of pre-scaled bf16 rows =====

template <int RELU>
__global__ __launch_bounds__(256) void agg_k(const ushort* __restrict__ Hin, size_t hstr,
                                             ushort* __restrict__ Hout,
                                             const int* __restrict__ csr, size_t cstr,
                                             const int* __restrict__ start,
                                             const int* __restrict__ degc,
                                             const float* __restrict__ dinv, int nstr,
                                             const float* __restrict__ bias,
                                             int N, int gbase) {
    const int g = gbase + blockIdx.y;
    const int wid  = threadIdx.x >> 6;
    const int lane = threadIdx.x & 63;
    const int v = blockIdx.x * 4 + wid;
    if (v >= N) return;

    const uint* base = reinterpret_cast<const uint*>(Hin + (size_t)g * hstr);
    const int*  cs   = csr + (size_t)g * cstr;
    float dvv = dinv[(size_t)g * nstr + v];
    int s   = start[(size_t)g * nstr + v];
    int end = s + degc[(size_t)g * nstr + v];

    uint hp = base[(size_t)v * 64 + lane];
    float ax = bf_lo(hp);
    float ay = bf_hi(hp);

    for (int bs = s; bs < end; bs += 64) {
        int m = end - bs;
        if (m > 64) m = 64;
        int u_l = 0;
        if (lane < m) u_l = cs[bs + lane];
        int e = 0;
        for (; e + 8 <= m; e += 8) {
            uint p[8];
#pragma unroll
            for (int j = 0; j < 8; ++j) {
                int u = __shfl(u_l, e + j);
                p[j] = base[(size_t)u * 64 + lane];
            }
#pragma unroll
            for (int j = 0; j < 8; ++j) { ax += bf_lo(p[j]); ay += bf_hi(p[j]); }
        }
        if (e + 4 <= m) {
            uint p[4];
#pragma unroll
            for (int j = 0; j < 4; ++j) {
                int u = __shfl(u_l, e + j);
                p[j] = base[(size_t)u * 64 + lane];
            }
#pragma unroll
            for (int j = 0; j < 4; ++j) { ax += bf_lo(p[j]); ay += bf_hi(p[j]); }
            e += 4;
        }
        for (; e < m; ++e) {
            int u = __shfl(u_l, e);
            uint p = base[(size_t)u * 64 + lane];
            ax += bf_lo(p);
            ay += bf_hi(p);
        }
    }

    float2 b = reinterpret_cast<const float2*>(bias)[lane];
    float ox = fmaf(dvv, ax, b.x);
    float oy = fmaf(dvv, ay, b.y);
    if (RELU) {
        ox = fmaxf(ox, 0.f);
        oy = fmaxf(oy, 0.f);
    }
    uint packed = (uint)f2bf(ox) | ((uint)f2bf(oy) << 16);
    reinterpret_cast<uint*>(Hout + (size_t)g * hstr)[(size_t)v * 64 + lane] = packed;
}

// ===== column stats over bf16 H =====

__global__ __launch_bounds__(256) void colstats_k(const ushort* __restrict__ H, size_t hstr,
                                                  float* __restrict__ stats, int sstr,
                                                  int N, int gbase) {
    const int g = gbase + blockIdx.y;
    __shared__ float4 red[4][64];
    const int t  = threadIdx.x;
    const int cp = t & 63;
    const int rg = t >> 6;
    const int r0 = blockIdx.x * 512;
    const int r1 = min(r0 + 512, N);

    const uint* base = reinterpret_cast<const uint*>(H + (size_t)g * hstr);
    float sx = 0.f, qx = 0.f, sy = 0.f, qy = 0.f;
    for (int r = r0 + rg; r < r1; r += 4) {
        uint p = base[(size_t)r * 64 + cp];
        float a = bf_lo(p), b = bf_hi(p);
        sx += a; qx = fmaf(a, a, qx);
        sy += b; qy = fmaf(b, b, qy);
    }
    red[rg][cp] = make_float4(sx, qx, sy, qy);
    __syncthreads();
    if (rg == 0) {
        float4 a0 = red[0][cp], a1 = red[1][cp], a2 = red[2][cp], a3 = red[3][cp];
        float* st = stats + (size_t)g * sstr + (size_t)(blockIdx.x & 7) * 256;
        atomicAdd(&st[cp * 2],           a0.x + a1.x + a2.x + a3.x);
        atomicAdd(&st[cp * 2 + 1],       a0.z + a1.z + a2.z + a3.z);
        atomicAdd(&st[128 + cp * 2],     a0.y + a1.y + a2.y + a3.y);
        atomicAdd(&st[128 + cp * 2 + 1], a0.w + a1.w + a2.w + a3.w);
    }
}

// ================= colnorm: bf16 in -> f32 out =================

__global__ __launch_bounds__(256) void colnorm_k(const ushort* __restrict__ H, size_t hstr,
                                                 const float* __restrict__ stats, int sstr,
                                                 float* __restrict__ Out,
                                                 int N, int gbase) {
    const int g = gbase + blockIdx.y;
    __shared__ float mu_s[128], rs_s[128];
    const int t = threadIdx.x;
    const float* st = stats + (size_t)g * sstr;
    if (t < 128) {
        float s = 0.f, q = 0.f;
#pragma unroll
        for (int sl = 0; sl < 8; ++sl) {
            s += st[sl * 256 + t];
            q += st[sl * 256 + 128 + t];
        }
        float mu = s / (float)N;
        float var = (q - s * mu) / (float)(N - 1);
        mu_s[t] = mu;
        rs_s[t] = rsqrtf(var);
    }
    __syncthreads();

    const uint4* Hb = reinterpret_cast<const uint4*>(H + (size_t)g * hstr);
    float4* Ob = reinterpret_cast<float4*>(Out + (size_t)g * N * 128);
    size_t total = (size_t)N * 16;
    size_t stride = (size_t)gridDim.x * 256;
    for (size_t i = (size_t)blockIdx.x * 256 + t; i < total; i += stride) {
        uint4 p = Hb[i];
        int c0 = ((int)(i & 15)) * 8;
        float o[8] = {bf_lo(p.x), bf_hi(p.x), bf_lo(p.y), bf_hi(p.y),
                      bf_lo(p.z), bf_hi(p.z), bf_lo(p.w), bf_hi(p.w)};
        float4 r0, r1;
        r0.x = (o[0] - mu_s[c0 + 0]) * rs_s[c0 + 0];
        r0.y = (o[1] - mu_s[c0 + 1]) * rs_s[c0 + 1];
        r0.z = (o[2] - mu_s[c0 + 2]) * rs_s[c0 + 2];
        r0.w = (o[3] - mu_s[c0 + 3]) * rs_s[c0 + 3];
        r1.x = (o[4] - mu_s[c0 + 4]) * rs_s[c0 + 4];
        r1.y = (o[5] - mu_s[c0 + 5]) * rs_s[c0 + 5];
        r1.z = (o[6] - mu_s[c0 + 6]) * rs_s[c0 + 6];
        r1.w = (o[7] - mu_s[c0 + 7]) * rs_s[c0 + 7];
        Ob[i * 2]     = r0;
        Ob[i * 2 + 1] = r1;
    }
}

// ================= driver =================

extern "C" void kernel_launch(void* const* d_in, const int* in_sizes, int n_in,
                              void* d_out, int out_size, void* d_ws, size_t ws_size,
                              hipStream_t stream) {
    const float* x1  = (const float*)d_in[0];
    const int*   ei1 = (const int*)d_in[1];
    const float* x2  = (const float*)d_in[2];
    const int*   ei2 = (const int*)d_in[3];
    const float* W0  = (const float*)d_in[4];
    const float* b0  = (const float*)d_in[5];
    const float* W1  = (const float*)d_in[6];
    const float* b1  = (const float*)d_in[7];

    const int N  = in_sizes[0] / 256;
    const int E1 = in_sizes[1] / 2;
    const int E2 = in_sizes[3] / 2;
    const int Emax = E1 > E2 ? E1 : E2;

    const int NB = CDIV(N, 256);
    int cap = (Emax / NB) * 8 / 5 + 1024;
    const int CAP = (cap + 1023) & ~1023;

    size_t szH = (size_t)N * 128 * 2;
    size_t need_merged = 2 * szH * 2
                       + (size_t)2 * N * 4 * 3
                       + (size_t)2 * NB * CAP * 4
                       + 64 * 1024 + 32 * 1024
                       + 2 * 8 * 256 * 4 + 2 * NB * 4
                       + 16 * 256;
    const bool merged = ws_size >= need_merged;
    const int  G = merged ? 2 : 1;

    const size_t hstr   = merged ? (size_t)N * 128 : 0;
    const int    nstr   = merged ? N : 0;
    const size_t cstr   = merged ? (size_t)NB * CAP : 0;
    const int    bstr   = merged ? NB : 0;
    const int    sstr   = merged ? 8 * 256 : 0;
    const size_t binstr = merged ? (size_t)N * 64 : 0;

    char* base = (char*)d_ws;
    size_t off = 0;
    auto carve = [&](size_t bytes) -> char* {
        char* p = base + off;
        off = (off + bytes + 255) & ~(size_t)255;
        return p;
    };
    ushort* hA    = (ushort*)carve(szH * G);     // aliases binned
    ushort* hB    = (ushort*)carve(szH * G);
    float*  dinv  = (float*)carve((size_t)N * 4 * G);
    int*    degc  = (int*)carve((size_t)N * 4 * G);
    int*    startA= (int*)carve((size_t)N * 4 * G);
    int*    csr   = (int*)carve((size_t)NB * CAP * 4 * G);
    ushort* Wp0   = (ushort*)carve((256 / 32) * 8 * 64 * 8 * 2);
    ushort* Wp1   = (ushort*)carve((128 / 32) * 8 * 64 * 8 * 2);
    float*  stats = (float*)carve(8 * 256 * 4 * G);
    int*    bcur  = (int*)carve((size_t)NB * 4 * G);
    uint*   binned = (uint*)hA;

    pack_w_k<<<CDIV((256 / 32) * 8 * 64, 256), 256, 0, stream>>>(W0, Wp0, 256);
    pack_w_k<<<CDIV((128 / 32) * 8 * 64, 256), 256, 0, stream>>>(W1, Wp1, 128);

    const int npass = merged ? 1 : 2;
    for (int pass = 0; pass < npass; ++pass) {
        const int gbase = merged ? 0 : pass;

        hipMemsetAsync(bcur, 0, (size_t)NB * 4 * G, stream);
        hipMemsetAsync(stats, 0, 8 * 256 * 4 * G, stream);

        binA_k<<<dim3(CDIV(Emax, 4096), G), 256, 0, stream>>>(
            ei1, ei2, E1, E2, NB, CAP, gbase, bcur, bstr, binned, binstr);
        binB_k<<<dim3(NB, G), 256, 0, stream>>>(
            binned, binstr, bcur, bstr, N, CAP, gbase, csr, cstr, startA, degc, dinv, nstr);

        // conv1: hA = dinv .* (x @ W0) ; hB = relu(dinv.*sum + b0)  [bf16]
        gemm_mfma<256, float><<<dim3(CDIV(N, 64), G), 256, 0, stream>>>(
            x1, x2, (const float4*)Wp0, dinv, nstr, hA, hstr, N, gbase);
        agg_k<1><<<dim3(CDIV(N, 4), G), 256, 0, stream>>>(
            hA, hstr, hB, csr, cstr, startA, degc, dinv, nstr, b0, N, gbase);

        // conv2: hA = dinv .* (hB @ W1) ; hB = dinv.*sum + b1 [bf16]
        gemm_mfma<128, ushort><<<dim3(CDIV(N, 64), G), 256, 0, stream>>>(
            hB, hB + hstr, (const float4*)Wp1, dinv, nstr, hA, hstr, N, gbase);
        agg_k<0><<<dim3(CDIV(N, 4), G), 256, 0, stream>>>(
            hA, hstr, hB, csr, cstr, startA, degc, dinv, nstr, b1, N, gbase);

        // stats + colnorm: out = (hB - mu) / sd   [f32]
        colstats_k<<<dim3(CDIV(N, 512), G), 256, 0, stream>>>(
            hB, hstr, stats, sstr, N, gbase);
        colnorm_k<<<dim3(1024, G), 256, 0, stream>>>(
            hB, hstr, stats, sstr, (float*)d_out, N, gbase);
    }
}